// Round 2
// baseline (175.706 us; speedup 1.0000x reference)
//
#include <hip/hip_runtime.h>
#include <hip/hip_bf16.h>

typedef __attribute__((ext_vector_type(8))) short short8;
typedef __attribute__((ext_vector_type(4))) float f32x4;

#define MFMA16(a,b,c) __builtin_amdgcn_mfma_f32_16x16x32_bf16((a),(b),(c),0,0,0)

static __device__ __forceinline__ unsigned int f2bf(float f){
    unsigned int u = __float_as_uint(f);
    u += 0x7FFFu + ((u >> 16) & 1u);
    return u >> 16;
}

static __device__ __forceinline__ short8 pack8(float4 a, float4 b){
    short8 r;
    r[0]=(short)f2bf(a.x); r[1]=(short)f2bf(a.y);
    r[2]=(short)f2bf(a.z); r[3]=(short)f2bf(a.w);
    r[4]=(short)f2bf(b.x); r[5]=(short)f2bf(b.y);
    r[6]=(short)f2bf(b.z); r[7]=(short)f2bf(b.w);
    return r;
}

// ---- mask dtype sniffer: int32 bools are all in {0,1}; byte-bools packed
// into int words set bytes 1..3 somewhere in the first 4096 words.
__global__ void detect_mask_k(const int* __restrict__ m, int* __restrict__ flag){
    __shared__ int any_hi;
    if (threadIdx.x == 0) any_hi = 0;
    __syncthreads();
    int acc = 0;
    #pragma unroll
    for (int it = 0; it < 16; ++it)
        acc |= m[it*256 + threadIdx.x];
    if (acc & 0xFFFFFF00) atomicOr(&any_hi, 1);
    __syncthreads();
    if (threadIdx.x == 0) *flag = any_hi;   // 1 = byte layout, 0 = int32 layout
}

// ---------------- QKV projection ----------------
// Q,K: out^T = W * x^T  (C: row=o, col=n)  -> row-major q[(b*8+h)*1024+n][d]
// V:   out  = x * Wv^T  (C: row=n, col=o)  -> transposed vt[(b*8+h)*32+d][n]
__global__ __launch_bounds__(256) void qkv_proj_k(
    const float* __restrict__ nd,
    const float* __restrict__ Wqp, const float* __restrict__ bqp,
    const float* __restrict__ Wkp, const float* __restrict__ bkp,
    const float* __restrict__ Wvp, const float* __restrict__ bvp,
    unsigned short* __restrict__ qout, unsigned short* __restrict__ kout,
    unsigned short* __restrict__ vtout)
{
    __shared__ __align__(16) unsigned short xl[64*264];   // 64 rows x 256 (+8 pad) bf16
    const int tid = threadIdx.x;
    const int R0 = blockIdx.x * 64;   // flattened (b*N+n) row base, 128 blocks
    const int b  = R0 >> 10;
    const int n0 = R0 & 1023;

    #pragma unroll
    for (int it = 0; it < 16; ++it){
        int f4 = it*256 + tid;
        int r = f4 >> 6, c4 = f4 & 63;
        float4 v = *(const float4*)(nd + (size_t)(R0+r)*256 + c4*4);
        unsigned int lo = f2bf(v.x) | (f2bf(v.y) << 16);
        unsigned int hi = f2bf(v.z) | (f2bf(v.w) << 16);
        *(uint2*)&xl[r*264 + c4*4] = make_uint2(lo, hi);
    }
    __syncthreads();

    const int lane = tid & 63;
    const int w  = tid >> 6;
    const int ln = lane & 15;
    const int g  = lane >> 4;
    const int ow = w * 64;

    f32x4 acc[4][4];

    for (int which = 0; which < 2; ++which){
        const float* W  = which ? Wkp : Wqp;
        const float* bb = which ? bkp : bqp;
        unsigned short* op = which ? kout : qout;
        const float scl = which ? 1.0f : 0.17677669529663687f;  // Q gets 1/sqrt(32)
        #pragma unroll
        for (int a=0;a<4;++a){
            #pragma unroll
            for (int c=0;c<4;++c) acc[a][c] = (f32x4){0.f,0.f,0.f,0.f};
        }
        for (int kk = 0; kk < 8; ++kk){
            short8 wf[4], xf[4];
            #pragma unroll
            for (int ot=0; ot<4; ++ot){
                const float* wp = W + (size_t)(ow + ot*16 + ln)*256 + kk*32 + g*8;
                wf[ot] = pack8(*(const float4*)wp, *(const float4*)(wp+4));
            }
            #pragma unroll
            for (int nt=0; nt<4; ++nt)
                xf[nt] = *(const short8*)&xl[(nt*16+ln)*264 + kk*32 + g*8];
            #pragma unroll
            for (int ot=0; ot<4; ++ot){
                #pragma unroll
                for (int nt=0; nt<4; ++nt)
                    acc[ot][nt] = MFMA16(wf[ot], xf[nt], acc[ot][nt]);
            }
        }
        #pragma unroll
        for (int ot=0; ot<4; ++ot){
            int o0 = ow + ot*16 + g*4;
            int h = o0 >> 5, d0 = o0 & 31;
            float4 b4 = *(const float4*)(bb + o0);
            #pragma unroll
            for (int nt=0; nt<4; ++nt){
                int n = n0 + nt*16 + ln;
                unsigned int lo = f2bf((acc[ot][nt][0]+b4.x)*scl) | (f2bf((acc[ot][nt][1]+b4.y)*scl)<<16);
                unsigned int hi = f2bf((acc[ot][nt][2]+b4.z)*scl) | (f2bf((acc[ot][nt][3]+b4.w)*scl)<<16);
                *(uint2*)(op + ((size_t)(b*8+h)*1024 + n)*32 + d0) = make_uint2(lo,hi);
            }
        }
    }

    // ---- V path (orientation 1), store transposed ----
    #pragma unroll
    for (int a=0;a<4;++a){
        #pragma unroll
        for (int c=0;c<4;++c) acc[a][c] = (f32x4){0.f,0.f,0.f,0.f};
    }
    for (int kk = 0; kk < 8; ++kk){
        short8 wf[4], xf[4];
        #pragma unroll
        for (int ot=0; ot<4; ++ot){
            const float* wp = Wvp + (size_t)(ow + ot*16 + ln)*256 + kk*32 + g*8;
            wf[ot] = pack8(*(const float4*)wp, *(const float4*)(wp+4));
        }
        #pragma unroll
        for (int nt=0; nt<4; ++nt)
            xf[nt] = *(const short8*)&xl[(nt*16+ln)*264 + kk*32 + g*8];
        #pragma unroll
        for (int nt=0; nt<4; ++nt){
            #pragma unroll
            for (int ot=0; ot<4; ++ot)
                acc[nt][ot] = MFMA16(xf[nt], wf[ot], acc[nt][ot]);
        }
    }
    #pragma unroll
    for (int nt=0; nt<4; ++nt){
        int nb = n0 + nt*16 + g*4;
        #pragma unroll
        for (int ot=0; ot<4; ++ot){
            int o = ow + ot*16 + ln;
            int h = o >> 5, d = o & 31;
            float bvv = bvp[o];
            unsigned int lo = f2bf(acc[nt][ot][0]+bvv) | (f2bf(acc[nt][ot][1]+bvv)<<16);
            unsigned int hi = f2bf(acc[nt][ot][2]+bvv) | (f2bf(acc[nt][ot][3]+bvv)<<16);
            *(uint2*)(vtout + ((size_t)(b*8+h)*32 + d)*1024 + nb) = make_uint2(lo,hi);
        }
    }
}

// ---------------- Fused biased-masked attention ----------------
// Block = (b, 16 q rows). 4 waves x 2 heads. S^T = mfma(K,Q); O^T = mfma(V^T,P^T).
__global__ __launch_bounds__(256) void attn_k(
    const unsigned short* __restrict__ qbuf, const unsigned short* __restrict__ kbuf,
    const unsigned short* __restrict__ vtbuf, const float* __restrict__ bias,
    const int* __restrict__ mask, const int* __restrict__ mflag,
    unsigned short* __restrict__ ab)
{
    __shared__ __align__(16) float bs[16*260];        // bias tile [16q][256(+4)] f32
    __shared__ __align__(4) unsigned char msk[16*36]; // mask tile [16q][32(+4)] bytes
    const int tid = threadIdx.x;
    const int bi  = blockIdx.x;        // 512 blocks = 8 b * 64 q-blocks
    const int b   = bi >> 6;
    const int q0  = (bi & 63) * 16;
    const int lane = tid & 63;
    const int w  = tid >> 6;
    const int ln = lane & 15;
    const int g  = lane >> 4;
    const bool bytemask = (*mflag != 0);   // uniform across grid

    short8 qf[2];
    #pragma unroll
    for (int h2 = 0; h2 < 2; ++h2){
        int h = w*2 + h2;
        qf[h2] = *(const short8*)(qbuf + ((size_t)(b*8+h)*1024 + q0 + ln)*32 + g*8);
    }
    f32x4 acc[2][2];
    #pragma unroll
    for (int i=0;i<2;++i){ acc[i][0]=(f32x4){0.f,0.f,0.f,0.f}; acc[i][1]=(f32x4){0.f,0.f,0.f,0.f}; }
    float m_[2] = {-1e30f, -1e30f};
    float l_[2] = {0.f, 0.f};
    const f32x4 z4 = {0.f,0.f,0.f,0.f};

    for (int c = 0; c < 32; ++c){
        const int c0 = c*32;
        __syncthreads();
        // stage bias tile: 16q x 32k x 8h fp32, fully coalesced
        #pragma unroll
        for (int it=0; it<4; ++it){
            int f4 = it*256 + tid;
            int q = f4 >> 6, cc = f4 & 63;
            float4 v = *(const float4*)(bias + ((size_t)(b*1024 + q0 + q)*1024 + c0)*8 + cc*4);
            *(float4*)&bs[q*260 + cc*4] = v;
        }
        // stage mask tile (dtype-adaptive)
        if (bytemask){
            if (tid < 128){
                int q = tid >> 3, cc = tid & 7;
                *(unsigned int*)&msk[q*36 + cc*4] =
                    *(const unsigned int*)((const unsigned char*)mask +
                        (size_t)(b*1024 + q0 + q)*1024 + c0 + cc*4);
            }
        } else {
            #pragma unroll
            for (int it=0; it<2; ++it){
                int idx = it*256 + tid;
                int q = idx >> 5, col = idx & 31;
                msk[q*36 + col] =
                    (unsigned char)(mask[(size_t)(b*1024 + q0 + q)*1024 + c0 + col] != 0);
            }
        }
        __syncthreads();

        #pragma unroll
        for (int h2 = 0; h2 < 2; ++h2){
            const int h = w*2 + h2;
            const size_t kbase = (size_t)(b*8+h)*1024 + c0;
            short8 kf0 = *(const short8*)(kbuf + (kbase + ln)*32 + g*8);
            short8 kf1 = *(const short8*)(kbuf + (kbase + 16 + ln)*32 + g*8);
            f32x4 s0 = MFMA16(kf0, qf[h2], z4);   // S^T[key][q], row=key, col=q
            f32x4 s1 = MFMA16(kf1, qf[h2], z4);
            float p[8];
            float mx = -1e30f;
            #pragma unroll
            for (int t=0; t<2; ++t){
                #pragma unroll
                for (int r=0; r<4; ++r){
                    int keyl = t*16 + g*4 + r;
                    float sv = (t ? s1[r] : s0[r]) + bs[ln*260 + keyl*8 + h];
                    bool dead = (msk[ln*36 + keyl] != 0) && ((c0 + keyl) != 0); // col 0 force-unmasked
                    sv = dead ? -1e30f : sv;
                    p[t*4+r] = sv;
                    mx = fmaxf(mx, sv);
                }
            }
            mx = fmaxf(mx, __shfl_xor(mx, 16));
            mx = fmaxf(mx, __shfl_xor(mx, 32));
            float mn = fmaxf(m_[h2], mx);
            float alpha = __expf(m_[h2] - mn);
            m_[h2] = mn;
            float ps = 0.f;
            #pragma unroll
            for (int i=0;i<8;++i){ p[i] = __expf(p[i]-mn); ps += p[i]; }
            ps += __shfl_xor(ps, 16);
            ps += __shfl_xor(ps, 32);
            l_[h2] = l_[h2]*alpha + ps;
            #pragma unroll
            for (int r=0;r<4;++r){ acc[h2][0][r]*=alpha; acc[h2][1][r]*=alpha; }

            // redistribute P^T (C-layout: key=4g+r per 16-tile) into B-frag layout (key=8g+j)
            short8 pf;
            #pragma unroll
            for (int j=0;j<8;++j){
                int src = ((g&1)*2 + (j>>2))*16 + ln;
                float a0 = __shfl(p[j&3],     src, 64);   // keys 0..15
                float a1 = __shfl(p[4+(j&3)], src, 64);   // keys 16..31
                pf[j] = (short)f2bf(g >= 2 ? a1 : a0);
            }
            const size_t vbase = (size_t)(b*8+h)*32;
            short8 vf0 = *(const short8*)(vtbuf + (vbase + ln)*1024 + c0 + g*8);
            short8 vf1 = *(const short8*)(vtbuf + (vbase + 16 + ln)*1024 + c0 + g*8);
            acc[h2][0] = MFMA16(vf0, pf, acc[h2][0]);   // O^T rows d 0..15
            acc[h2][1] = MFMA16(vf1, pf, acc[h2][1]);   // O^T rows d 16..31
        }
    }

    #pragma unroll
    for (int h2=0; h2<2; ++h2){
        const int h = w*2 + h2;
        float inv = 1.0f / l_[h2];
        int n = q0 + ln;
        #pragma unroll
        for (int dt=0; dt<2; ++dt){
            int d0 = dt*16 + g*4;
            unsigned int lo = f2bf(acc[h2][dt][0]*inv) | (f2bf(acc[h2][dt][1]*inv)<<16);
            unsigned int hi = f2bf(acc[h2][dt][2]*inv) | (f2bf(acc[h2][dt][3]*inv)<<16);
            *(uint2*)(ab + ((size_t)(b*1024 + n))*256 + h*32 + d0) = make_uint2(lo,hi);
        }
    }
}

// ---------------- Output projection ----------------
__global__ __launch_bounds__(256) void oproj_k(
    const unsigned short* __restrict__ ab, const float* __restrict__ Wop,
    const float* __restrict__ bop, float* __restrict__ out)
{
    __shared__ __align__(16) unsigned short al[64*264];
    const int tid = threadIdx.x;
    const int R0 = blockIdx.x * 64;
    #pragma unroll
    for (int it=0; it<8; ++it){
        int f8 = it*256 + tid;
        int r = f8 >> 5, c8 = f8 & 31;
        short8 v = *(const short8*)(ab + (size_t)(R0+r)*256 + c8*8);
        *(short8*)&al[r*264 + c8*8] = v;
    }
    __syncthreads();
    const int lane = tid & 63;
    const int w = tid >> 6, ln = lane & 15, g = lane >> 4;
    const int ow = w*64;
    f32x4 acc[4][4];
    #pragma unroll
    for (int a=0;a<4;++a){
        #pragma unroll
        for (int c=0;c<4;++c) acc[a][c]=(f32x4){0.f,0.f,0.f,0.f};
    }
    for (int kk=0;kk<8;++kk){
        short8 wf[4], xf[4];
        #pragma unroll
        for (int ot=0;ot<4;++ot){
            const float* wp = Wop + (size_t)(ow+ot*16+ln)*256 + kk*32 + g*8;
            wf[ot] = pack8(*(const float4*)wp, *(const float4*)(wp+4));
        }
        #pragma unroll
        for (int nt=0;nt<4;++nt)
            xf[nt] = *(const short8*)&al[(nt*16+ln)*264 + kk*32 + g*8];
        #pragma unroll
        for (int ot=0;ot<4;++ot){
            #pragma unroll
            for (int nt=0;nt<4;++nt)
                acc[ot][nt] = MFMA16(wf[ot], xf[nt], acc[ot][nt]);
        }
    }
    #pragma unroll
    for (int ot=0;ot<4;++ot){
        int o0 = ow + ot*16 + g*4;
        float4 b4 = *(const float4*)(bop + o0);
        #pragma unroll
        for (int nt=0;nt<4;++nt){
            int n = R0 + nt*16 + ln;
            float4 res;
            res.x = acc[ot][nt][0] + b4.x;
            res.y = acc[ot][nt][1] + b4.y;
            res.z = acc[ot][nt][2] + b4.z;
            res.w = acc[ot][nt][3] + b4.w;
            *(float4*)(out + (size_t)n*256 + o0) = res;
        }
    }
}

extern "C" void kernel_launch(void* const* d_in, const int* in_sizes, int n_in,
                              void* d_out, int out_size, void* d_ws, size_t ws_size,
                              hipStream_t stream)
{
    (void)in_sizes; (void)n_in; (void)out_size; (void)ws_size;
    const float* nd   = (const float*)d_in[0];
    // d_in[1] = N scalar (compile-time 1024 here)
    const float* bias = (const float*)d_in[2];
    const int* mask   = (const int*)d_in[3];
    const float* Wq = (const float*)d_in[4];
    const float* bq = (const float*)d_in[5];
    const float* Wk = (const float*)d_in[6];
    const float* bk = (const float*)d_in[7];
    const float* Wv = (const float*)d_in[8];
    const float* bv = (const float*)d_in[9];
    const float* Wo = (const float*)d_in[10];
    const float* bo = (const float*)d_in[11];
    float* out = (float*)d_out;

    const size_t ELEMS = (size_t)8*8*1024*32;   // 2M bf16 per buffer
    unsigned short* qb  = (unsigned short*)d_ws;
    unsigned short* kb  = qb  + ELEMS;
    unsigned short* vtb = kb  + ELEMS;
    unsigned short* ab  = vtb + ELEMS;
    int* mflag = (int*)(ab + ELEMS);

    detect_mask_k<<<1, 256, 0, stream>>>(mask, mflag);
    qkv_proj_k<<<128, 256, 0, stream>>>(nd, Wq, bq, Wk, bk, Wv, bv, qb, kb, vtb);
    attn_k<<<512, 256, 0, stream>>>(qb, kb, vtb, bias, mask, mflag, ab);
    oproj_k<<<128, 256, 0, stream>>>(ab, Wo, bo, out);
}

// Round 3
// 146.946 us; speedup vs baseline: 1.1957x; 1.1957x over previous
//
#include <hip/hip_runtime.h>
#include <hip/hip_bf16.h>

typedef __attribute__((ext_vector_type(8))) short short8;
typedef __attribute__((ext_vector_type(4))) float f32x4;

#define MFMA16(a,b,c) __builtin_amdgcn_mfma_f32_16x16x32_bf16((a),(b),(c),0,0,0)

static __device__ __forceinline__ unsigned int f2bf(float f){
    unsigned int u = __float_as_uint(f);
    u += 0x7FFFu + ((u >> 16) & 1u);
    return u >> 16;
}

static __device__ __forceinline__ short8 pack8(float4 a, float4 b){
    short8 r;
    r[0]=(short)f2bf(a.x); r[1]=(short)f2bf(a.y);
    r[2]=(short)f2bf(a.z); r[3]=(short)f2bf(a.w);
    r[4]=(short)f2bf(b.x); r[5]=(short)f2bf(b.y);
    r[6]=(short)f2bf(b.z); r[7]=(short)f2bf(b.w);
    return r;
}

// ---- mask dtype sniffer: int32 bools are all in {0,1}; byte-bools packed
// into int words set bytes 1..3 somewhere in the first 4096 words.
__global__ void detect_mask_k(const int* __restrict__ m, int* __restrict__ flag){
    __shared__ int any_hi;
    if (threadIdx.x == 0) any_hi = 0;
    __syncthreads();
    int acc = 0;
    #pragma unroll
    for (int it = 0; it < 16; ++it)
        acc |= m[it*256 + threadIdx.x];
    if (acc & 0xFFFFFF00) atomicOr(&any_hi, 1);
    __syncthreads();
    if (threadIdx.x == 0) *flag = any_hi;   // 1 = byte layout, 0 = int32 layout
}

// ---- mask -> bit-packed [b][q][32 words] (1 bit per key, 1 = masked/-inf)
__global__ __launch_bounds__(256) void mask_prep_k(
    const unsigned int* __restrict__ m, const int* __restrict__ flag,
    unsigned int* __restrict__ bmout)
{
    const int tid  = threadIdx.x;
    const int lane = tid & 63;
    const unsigned int gbase = blockIdx.x*256u + tid;
    if (*flag == 0){
        // int32 layout: 8388608 words, ballot 64 -> one u64 per wave-iter
        for (int it = 0; it < 32; ++it){
            unsigned int idx = it*262144u + gbase;
            unsigned int v = m[idx];
            unsigned long long bal = __ballot(v != 0u);
            if (lane == 0)
                *(unsigned long long*)(bmout + (idx >> 5)) = bal;  // idx mult of 64
        }
    } else {
        // byte layout: 2097152 u32 words (4 bools each)
        for (int it = 0; it < 8; ++it){
            unsigned int idx = it*262144u + gbase;
            unsigned int v = m[idx];
            unsigned int nib = (v | (v>>7) | (v>>14) | (v>>21)) & 0xFu;
            unsigned int x = nib << ((lane & 7)*4);
            x |= (unsigned int)__shfl_xor((int)x, 1);
            x |= (unsigned int)__shfl_xor((int)x, 2);
            x |= (unsigned int)__shfl_xor((int)x, 4);
            if ((lane & 7) == 0)
                bmout[idx >> 3] = x;   // idx mult of 8 here
        }
    }
}

// ---------------- QKV projection (3-way split grid) ----------------
// kind 0: Q = scale*(x Wq^T + bq) -> row-major q[(b*8+h)*1024+n][d]
// kind 1: K                        -> row-major k[...]
// kind 2: V                        -> transposed vt[(b*8+h)*32+d][n]
__global__ __launch_bounds__(256) void qkv_proj_k(
    const float* __restrict__ nd,
    const float* __restrict__ Wqp, const float* __restrict__ bqp,
    const float* __restrict__ Wkp, const float* __restrict__ bkp,
    const float* __restrict__ Wvp, const float* __restrict__ bvp,
    unsigned short* __restrict__ qout, unsigned short* __restrict__ kout,
    unsigned short* __restrict__ vtout)
{
    __shared__ __align__(16) unsigned short xl[64*264];
    const int tid  = threadIdx.x;
    const int bi   = blockIdx.x;          // 384 = 3 kinds x 128 tiles
    const int kind = bi >> 7;
    const int R0   = (bi & 127) * 64;
    const int b    = R0 >> 10;
    const int n0   = R0 & 1023;

    #pragma unroll
    for (int it = 0; it < 16; ++it){
        int f4 = it*256 + tid;
        int r = f4 >> 6, c4 = f4 & 63;
        float4 v = *(const float4*)(nd + (size_t)(R0+r)*256 + c4*4);
        unsigned int lo = f2bf(v.x) | (f2bf(v.y) << 16);
        unsigned int hi = f2bf(v.z) | (f2bf(v.w) << 16);
        *(uint2*)&xl[r*264 + c4*4] = make_uint2(lo, hi);
    }
    __syncthreads();

    const int lane = tid & 63;
    const int w  = tid >> 6;
    const int ln = lane & 15;
    const int g  = lane >> 4;
    const int ow = w * 64;

    f32x4 acc[4][4];
    #pragma unroll
    for (int a=0;a<4;++a){
        #pragma unroll
        for (int c=0;c<4;++c) acc[a][c] = (f32x4){0.f,0.f,0.f,0.f};
    }

    if (kind < 2){
        const float* W  = kind ? Wkp : Wqp;
        const float* bb = kind ? bkp : bqp;
        unsigned short* op = kind ? kout : qout;
        const float scl = kind ? 1.0f : 0.17677669529663687f;  // Q gets 1/sqrt(32)
        for (int kk = 0; kk < 8; ++kk){
            short8 wf[4], xf[4];
            #pragma unroll
            for (int ot=0; ot<4; ++ot){
                const float* wp = W + (size_t)(ow + ot*16 + ln)*256 + kk*32 + g*8;
                wf[ot] = pack8(*(const float4*)wp, *(const float4*)(wp+4));
            }
            #pragma unroll
            for (int nt=0; nt<4; ++nt)
                xf[nt] = *(const short8*)&xl[(nt*16+ln)*264 + kk*32 + g*8];
            #pragma unroll
            for (int ot=0; ot<4; ++ot){
                #pragma unroll
                for (int nt=0; nt<4; ++nt)
                    acc[ot][nt] = MFMA16(wf[ot], xf[nt], acc[ot][nt]);
            }
        }
        #pragma unroll
        for (int ot=0; ot<4; ++ot){
            int o0 = ow + ot*16 + g*4;
            int h = o0 >> 5, d0 = o0 & 31;
            float4 b4 = *(const float4*)(bb + o0);
            #pragma unroll
            for (int nt=0; nt<4; ++nt){
                int n = n0 + nt*16 + ln;
                unsigned int lo = f2bf((acc[ot][nt][0]+b4.x)*scl) | (f2bf((acc[ot][nt][1]+b4.y)*scl)<<16);
                unsigned int hi = f2bf((acc[ot][nt][2]+b4.z)*scl) | (f2bf((acc[ot][nt][3]+b4.w)*scl)<<16);
                *(uint2*)(op + ((size_t)(b*8+h)*1024 + n)*32 + d0) = make_uint2(lo,hi);
            }
        }
    } else {
        for (int kk = 0; kk < 8; ++kk){
            short8 wf[4], xf[4];
            #pragma unroll
            for (int ot=0; ot<4; ++ot){
                const float* wp = Wvp + (size_t)(ow + ot*16 + ln)*256 + kk*32 + g*8;
                wf[ot] = pack8(*(const float4*)wp, *(const float4*)(wp+4));
            }
            #pragma unroll
            for (int nt=0; nt<4; ++nt)
                xf[nt] = *(const short8*)&xl[(nt*16+ln)*264 + kk*32 + g*8];
            #pragma unroll
            for (int nt=0; nt<4; ++nt){
                #pragma unroll
                for (int ot=0; ot<4; ++ot)
                    acc[nt][ot] = MFMA16(xf[nt], wf[ot], acc[nt][ot]);
            }
        }
        #pragma unroll
        for (int nt=0; nt<4; ++nt){
            int nb = n0 + nt*16 + g*4;
            #pragma unroll
            for (int ot=0; ot<4; ++ot){
                int o = ow + ot*16 + ln;
                int h = o >> 5, d = o & 31;
                float bvv = bvp[o];
                unsigned int lo = f2bf(acc[nt][ot][0]+bvv) | (f2bf(acc[nt][ot][1]+bvv)<<16);
                unsigned int hi = f2bf(acc[nt][ot][2]+bvv) | (f2bf(acc[nt][ot][3]+bvv)<<16);
                *(uint2*)(vtout + ((size_t)(b*8+h)*32 + d)*1024 + nb) = make_uint2(lo,hi);
            }
        }
    }
}

// ---------------- Fused biased-masked attention ----------------
// Block = (b, 16 q rows), 512 threads = 8 waves, 1 head/wave.
// Pipelined: chunk c+1 global loads issued before compute(c).
// LDS bias layout: X = ((4t+r)*8 + h)*4 + g; W = X*16 + (q ^ ((X>>4)&15))
//   -> 2-way (free) bank access on both ds_write and per-h scalar reads.
__global__ __launch_bounds__(512, 4) void attn_k(
    const unsigned short* __restrict__ qbuf, const unsigned short* __restrict__ kbuf,
    const unsigned short* __restrict__ vtbuf, const float* __restrict__ bias,
    const unsigned int* __restrict__ bm, unsigned short* __restrict__ ab)
{
    __shared__ float bs[4096];   // 16KB
    const int tid  = threadIdx.x;
    const int bi   = blockIdx.x;        // 512 = 8 b * 64 q-tiles
    const int b    = bi >> 6;
    const int q0   = (bi & 63) * 16;
    const int lane = tid & 63;
    const int w    = tid >> 6;          // wave = head
    const int ln   = lane & 15;
    const int g    = lane >> 4;

    // Q fragment (B-operand): col=q=ln, k=d=g*8..
    const short8 qf = *(const short8*)(qbuf + ((size_t)(b*8+w)*1024 + q0 + ln)*32 + g*8);

    // staging decode: thread stages granule `lane` of rows q=2w, 2w+1
    const int h2s  = lane & 1;
    const int keys = lane >> 1;
    const int ts   = keys >> 4;
    const int rs   = keys & 3;
    const int gs   = (keys >> 2) & 3;
    const int base0 = (128*ts + 32*rs + 16*h2s + gs) * 16;
    const int xrs   = (8*ts + 2*rs + h2s) & 15;
    const int qxa   = (2*w)     ^ xrs;
    const int qxb   = (2*w + 1) ^ xrs;

    const float* bp0 = bias + ((size_t)(b*1024 + q0 + 2*w)*1024)*8 + lane*4;
    const unsigned short* kp = kbuf  + ((size_t)(b*8+w)*1024 + ln)*32 + g*8;
    const unsigned short* vp = vtbuf + ((size_t)(b*8+w)*32   + ln)*1024 + g*8;
    const unsigned int*  bmp = bm + (size_t)(b*1024 + q0 + ln)*32;

    f32x4 acc0 = (f32x4){0.f,0.f,0.f,0.f};
    f32x4 acc1 = (f32x4){0.f,0.f,0.f,0.f};
    float m_ = -1e30f, l_ = 0.f;
    const f32x4 z4 = {0.f,0.f,0.f,0.f};

    // prologue: issue chunk-0 loads
    float4 ba  = *(const float4*)(bp0);
    float4 bb2 = *(const float4*)(bp0 + 8192);
    short8 kn0 = *(const short8*)(kp);
    short8 kn1 = *(const short8*)(kp + 512);       // +16 keys * 32
    short8 vn0 = *(const short8*)(vp);
    short8 vn1 = *(const short8*)(vp + 16*1024);
    unsigned int bmn = bmp[0] & ~1u;               // col 0 force-unmasked

    for (int c = 0; c < 32; ++c){
        // write staged bias chunk c into LDS (waits its loads implicitly)
        bs[base0       + qxa] = ba.x;  bs[base0 +  64 + qxa] = ba.y;
        bs[base0 + 128 + qxa] = ba.z;  bs[base0 + 192 + qxa] = ba.w;
        bs[base0       + qxb] = bb2.x; bs[base0 +  64 + qxb] = bb2.y;
        bs[base0 + 128 + qxb] = bb2.z; bs[base0 + 192 + qxb] = bb2.w;

        short8 kc0 = kn0, kc1 = kn1, vc0 = vn0, vc1 = vn1;
        unsigned int bmc = bmn;

        if (c < 31){   // issue chunk c+1 loads — in flight across barriers+compute
            int c1 = c + 1;
            ba  = *(const float4*)(bp0 + c1*256);
            bb2 = *(const float4*)(bp0 + c1*256 + 8192);
            kn0 = *(const short8*)(kp + c1*1024);
            kn1 = *(const short8*)(kp + c1*1024 + 512);
            vn0 = *(const short8*)(vp + c1*32);
            vn1 = *(const short8*)(vp + c1*32 + 16*1024);
            bmn = bmp[c1];
        }
        __syncthreads();

        // ---- compute chunk c ----
        f32x4 s0 = MFMA16(kc0, qf, z4);   // S^T: col=q=ln, row=key=4g+r (keys 0..15)
        f32x4 s1 = MFMA16(kc1, qf, z4);   // keys 16..31

        float pv[8];
        float mx = -1e30f;
        #pragma unroll
        for (int t=0; t<2; ++t){
            #pragma unroll
            for (int r=0; r<4; ++r){
                int keyl = t*16 + g*4 + r;
                int bidx = (t*128 + r*32 + w*4 + g)*16 + (ln ^ ((t*8 + r*2 + (w>>2)) & 15));
                float sv = (t ? s1[r] : s0[r]) + bs[bidx];
                sv = ((bmc >> keyl) & 1u) ? -1e30f : sv;
                pv[t*4+r] = sv;
                mx = fmaxf(mx, sv);
            }
        }
        mx = fmaxf(mx, __shfl_xor(mx, 16));
        mx = fmaxf(mx, __shfl_xor(mx, 32));
        float mn = fmaxf(m_, mx);
        float alpha = __expf(m_ - mn);
        m_ = mn;
        float ps = 0.f;
        #pragma unroll
        for (int i=0;i<8;++i){ pv[i] = __expf(pv[i]-mn); ps += pv[i]; }
        ps += __shfl_xor(ps, 16);
        ps += __shfl_xor(ps, 32);
        l_ = l_*alpha + ps;
        #pragma unroll
        for (int r=0;r<4;++r){ acc0[r]*=alpha; acc1[r]*=alpha; }

        // redistribute P^T into B-frag layout: pack bf16 pairs, then 8 shuffles
        unsigned int A01 = f2bf(pv[0]) | (f2bf(pv[1])<<16);
        unsigned int A23 = f2bf(pv[2]) | (f2bf(pv[3])<<16);
        unsigned int B01 = f2bf(pv[4]) | (f2bf(pv[5])<<16);
        unsigned int B23 = f2bf(pv[6]) | (f2bf(pv[7])<<16);
        int s0l = (2*(g&1))*16 + ln;
        int s1l = s0l + 16;
        unsigned int a01  = (unsigned int)__shfl((int)A01, s0l);
        unsigned int a23  = (unsigned int)__shfl((int)A23, s0l);
        unsigned int b01  = (unsigned int)__shfl((int)B01, s0l);
        unsigned int b23  = (unsigned int)__shfl((int)B23, s0l);
        unsigned int a01b = (unsigned int)__shfl((int)A01, s1l);
        unsigned int a23b = (unsigned int)__shfl((int)A23, s1l);
        unsigned int b01b = (unsigned int)__shfl((int)B01, s1l);
        unsigned int b23b = (unsigned int)__shfl((int)B23, s1l);
        bool hi = (g >= 2);
        int4 pw = make_int4((int)(hi ? b01  : a01 ), (int)(hi ? b23  : a23 ),
                            (int)(hi ? b01b : a01b), (int)(hi ? b23b : a23b));
        short8 pf = *(short8*)&pw;

        acc0 = MFMA16(vc0, pf, acc0);   // O^T rows d 0..15
        acc1 = MFMA16(vc1, pf, acc1);   // O^T rows d 16..31
        __syncthreads();
    }

    float inv = 1.0f / l_;
    {
        int n = q0 + ln;
        unsigned int lo0 = f2bf(acc0[0]*inv) | (f2bf(acc0[1]*inv)<<16);
        unsigned int hi0 = f2bf(acc0[2]*inv) | (f2bf(acc0[3]*inv)<<16);
        *(uint2*)(ab + ((size_t)(b*1024 + n))*256 + w*32 + g*4) = make_uint2(lo0,hi0);
        unsigned int lo1 = f2bf(acc1[0]*inv) | (f2bf(acc1[1]*inv)<<16);
        unsigned int hi1 = f2bf(acc1[2]*inv) | (f2bf(acc1[3]*inv)<<16);
        *(uint2*)(ab + ((size_t)(b*1024 + n))*256 + w*32 + 16 + g*4) = make_uint2(lo1,hi1);
    }
}

// ---------------- Output projection (32-row tiles) ----------------
__global__ __launch_bounds__(256) void oproj_k(
    const unsigned short* __restrict__ ab, const float* __restrict__ Wop,
    const float* __restrict__ bop, float* __restrict__ out)
{
    __shared__ __align__(16) unsigned short al[32*264];
    const int tid = threadIdx.x;
    const int R0 = blockIdx.x * 32;   // 256 blocks
    #pragma unroll
    for (int it=0; it<4; ++it){
        int f8 = it*256 + tid;
        int r = f8 >> 5, c8 = f8 & 31;
        *(short8*)&al[r*264 + c8*8] = *(const short8*)(ab + (size_t)(R0+r)*256 + c8*8);
    }
    __syncthreads();
    const int lane = tid & 63;
    const int w = tid >> 6, ln = lane & 15, g = lane >> 4;
    const int ow = w*64;
    f32x4 acc[4][2];
    #pragma unroll
    for (int a=0;a<4;++a){ acc[a][0]=(f32x4){0.f,0.f,0.f,0.f}; acc[a][1]=(f32x4){0.f,0.f,0.f,0.f}; }
    for (int kk=0;kk<8;++kk){
        short8 wf[4], xf[2];
        #pragma unroll
        for (int ot=0;ot<4;++ot){
            const float* wp = Wop + (size_t)(ow+ot*16+ln)*256 + kk*32 + g*8;
            wf[ot] = pack8(*(const float4*)wp, *(const float4*)(wp+4));
        }
        #pragma unroll
        for (int nt=0;nt<2;++nt)
            xf[nt] = *(const short8*)&al[(nt*16+ln)*264 + kk*32 + g*8];
        #pragma unroll
        for (int ot=0;ot<4;++ot){
            #pragma unroll
            for (int nt=0;nt<2;++nt)
                acc[ot][nt] = MFMA16(wf[ot], xf[nt], acc[ot][nt]);
        }
    }
    #pragma unroll
    for (int ot=0;ot<4;++ot){
        int o0 = ow + ot*16 + g*4;
        float4 b4 = *(const float4*)(bop + o0);
        #pragma unroll
        for (int nt=0;nt<2;++nt){
            int n = R0 + nt*16 + ln;
            float4 res;
            res.x = acc[ot][nt][0] + b4.x;
            res.y = acc[ot][nt][1] + b4.y;
            res.z = acc[ot][nt][2] + b4.z;
            res.w = acc[ot][nt][3] + b4.w;
            *(float4*)(out + (size_t)n*256 + o0) = res;
        }
    }
}

extern "C" void kernel_launch(void* const* d_in, const int* in_sizes, int n_in,
                              void* d_out, int out_size, void* d_ws, size_t ws_size,
                              hipStream_t stream)
{
    (void)in_sizes; (void)n_in; (void)out_size; (void)ws_size;
    const float* nd   = (const float*)d_in[0];
    // d_in[1] = N scalar (compile-time 1024 here)
    const float* bias = (const float*)d_in[2];
    const int* mask   = (const int*)d_in[3];
    const float* Wq = (const float*)d_in[4];
    const float* bq = (const float*)d_in[5];
    const float* Wk = (const float*)d_in[6];
    const float* bk = (const float*)d_in[7];
    const float* Wv = (const float*)d_in[8];
    const float* bv = (const float*)d_in[9];
    const float* Wo = (const float*)d_in[10];
    const float* bo = (const float*)d_in[11];
    float* out = (float*)d_out;

    const size_t ELEMS = (size_t)8*8*1024*32;   // 2M bf16 per buffer
    unsigned short* qb  = (unsigned short*)d_ws;
    unsigned short* kb  = qb  + ELEMS;
    unsigned short* vtb = kb  + ELEMS;
    unsigned short* ab  = vtb + ELEMS;
    unsigned int* bmw   = (unsigned int*)(ab + ELEMS);  // 1MB bitmask
    int* mflag          = (int*)(bmw + 262144);

    detect_mask_k<<<1, 256, 0, stream>>>(mask, mflag);
    mask_prep_k<<<1024, 256, 0, stream>>>((const unsigned int*)mask, mflag, bmw);
    qkv_proj_k<<<384, 256, 0, stream>>>(nd, Wq, bq, Wk, bk, Wv, bv, qb, kb, vtb);
    attn_k<<<512, 512, 0, stream>>>(qb, kb, vtb, bias, bmw, ab);
    oproj_k<<<256, 256, 0, stream>>>(ab, Wo, bo, out);
}